// Round 3
// baseline (820.306 us; speedup 1.0000x reference)
//
#include <hip/hip_runtime.h>

#define NN 50000
#define NE 1600000
#define DIM 256
#define OUTD 64
#define ALPHA 0.2f

#define BSH 8                       // bucket = src >> 8 (256 nodes/bucket)
#define NB ((NN + 255) >> 8)        // 196 coarse buckets
#define P1_BLOCKS 512
#define EPB (NE / P1_BLOCKS)        // 3125 edges per binning block
#define CAP 32                      // LDS bin capacity (avg fill ~16)

typedef unsigned int u32;

// ---------------------------------------------------------------------------
// h = x @ W  (fp32), plus per-node logit partials s1 = h.a[:64], s2 = h.a[64:]
// ---------------------------------------------------------------------------
__global__ __launch_bounds__(256) void gemm_h_kernel(
    const float* __restrict__ x, const float* __restrict__ W,
    const float* __restrict__ a, float* __restrict__ h,
    float* __restrict__ s1, float* __restrict__ s2)
{
  __shared__ float Wl[DIM][OUTD];  // 64 KB
  const int t = threadIdx.x;
  for (int i = t; i < DIM * OUTD; i += 256) Wl[i >> 6][i & 63] = W[i];
  __syncthreads();

  const int o = t & 63;
  const int rsub = __builtin_amdgcn_readfirstlane(t >> 6);  // wave id, SGPR
  const int row0 = blockIdx.x * 16;

  const float4* xr0 = (const float4*)(x + (size_t)(row0 + rsub) * DIM);
  const float4* xr1 = xr0 + DIM;
  const float4* xr2 = xr0 + 2 * DIM;
  const float4* xr3 = xr0 + 3 * DIM;

  float acc0 = 0.f, acc1 = 0.f, acc2 = 0.f, acc3 = 0.f;
#pragma unroll 2
  for (int k4 = 0; k4 < DIM / 4; ++k4) {
    const float4 u0 = xr0[k4], u1 = xr1[k4], u2 = xr2[k4], u3 = xr3[k4];
    const float w0 = Wl[4 * k4 + 0][o];
    const float w1 = Wl[4 * k4 + 1][o];
    const float w2 = Wl[4 * k4 + 2][o];
    const float w3 = Wl[4 * k4 + 3][o];
    acc0 = fmaf(u0.x, w0, acc0); acc0 = fmaf(u0.y, w1, acc0);
    acc0 = fmaf(u0.z, w2, acc0); acc0 = fmaf(u0.w, w3, acc0);
    acc1 = fmaf(u1.x, w0, acc1); acc1 = fmaf(u1.y, w1, acc1);
    acc1 = fmaf(u1.z, w2, acc1); acc1 = fmaf(u1.w, w3, acc1);
    acc2 = fmaf(u2.x, w0, acc2); acc2 = fmaf(u2.y, w1, acc2);
    acc2 = fmaf(u2.z, w2, acc2); acc2 = fmaf(u2.w, w3, acc2);
    acc3 = fmaf(u3.x, w0, acc3); acc3 = fmaf(u3.y, w1, acc3);
    acc3 = fmaf(u3.z, w2, acc3); acc3 = fmaf(u3.w, w3, acc3);
  }

  const float a1 = a[o];
  const float a2 = a[OUTD + o];
  float accs[4] = {acc0, acc1, acc2, acc3};
#pragma unroll
  for (int j = 0; j < 4; ++j) {
    const int r = row0 + rsub + 4 * j;
    h[(size_t)r * OUTD + o] = accs[j];
    float p1 = accs[j] * a1;
    float p2 = accs[j] * a2;
    for (int off = 32; off > 0; off >>= 1) {
      p1 += __shfl_xor(p1, off);
      p2 += __shfl_xor(p2, off);
    }
    if (o == 0) { s1[r] = p1; s2[r] = p2; }
  }
}

// ---------------------------------------------------------------------------
// Coarse-bucket histogram (LDS-local, then 196 global atomics per block).
// ---------------------------------------------------------------------------
__global__ __launch_bounds__(256) void hist_kernel(const int* __restrict__ src,
                                                   int* __restrict__ bhist) {
  __shared__ int lh[NB];
  for (int i = threadIdx.x; i < NB; i += 256) lh[i] = 0;
  __syncthreads();
  const int base = blockIdx.x * EPB;
  for (int i = threadIdx.x; i < EPB; i += 256)
    atomicAdd(&lh[src[base + i] >> BSH], 1);
  __syncthreads();
  for (int i = threadIdx.x; i < NB; i += 256)
    if (lh[i]) atomicAdd(&bhist[i], lh[i]);
}

// ---------------------------------------------------------------------------
// Scan 196 bucket counts -> bucket offsets + global append cursors.
// ---------------------------------------------------------------------------
__global__ __launch_bounds__(256) void bscan_kernel(const int* __restrict__ bhist,
                                                    int* __restrict__ bstart,
                                                    int* __restrict__ gcursor) {
  __shared__ int tmp[256];
  const int t = threadIdx.x;
  const int v = (t < NB) ? bhist[t] : 0;
  int x = v;
  tmp[t] = v;
  __syncthreads();
  for (int off = 1; off < 256; off <<= 1) {
    const int y = (t >= off) ? tmp[t - off] : 0;
    __syncthreads();
    x += y;
    tmp[t] = x;
    __syncthreads();
  }
  if (t < NB) { bstart[t] = x - v; gcursor[t] = x - v; }
  if (t == NB - 1) bstart[NB] = x;  // == NE
}

// ---------------------------------------------------------------------------
// Bin edges into coarse buckets with LDS staging; flush contiguous runs.
// packed = (src&255)<<16 | dst (both < 65536).
// ---------------------------------------------------------------------------
__global__ __launch_bounds__(256) void bin_kernel(const int* __restrict__ src,
                                                  const int* __restrict__ dst,
                                                  int* __restrict__ gcursor,
                                                  u32* __restrict__ binned) {
  __shared__ u32 buf[NB][CAP];  // ~25 KB
  __shared__ int cnt[NB];
  for (int i = threadIdx.x; i < NB; i += 256) cnt[i] = 0;
  __syncthreads();
  const int base = blockIdx.x * EPB;
  for (int i = threadIdx.x; i < EPB; i += 256) {
    const int s = src[base + i];
    const u32 packed = ((u32)(s & 255) << 16) | (u32)dst[base + i];
    const int b = s >> BSH;
    const int pos = atomicAdd(&cnt[b], 1);
    if (pos < CAP) buf[b][pos] = packed;
    else binned[atomicAdd(&gcursor[b], 1)] = packed;  // rare spill
  }
  __syncthreads();
  const int lane = threadIdx.x & 63;
  const int wv = threadIdx.x >> 6;
  for (int b = wv; b < NB; b += 4) {
    const int n = min(cnt[b], CAP);
    if (n == 0) continue;
    int rb = 0;
    if (lane == 0) rb = atomicAdd(&gcursor[b], n);
    rb = __shfl(rb, 0);
    for (int j = lane; j < n; j += 64) binned[rb + j] = buf[b][j];
  }
}

// ---------------------------------------------------------------------------
// Per-bucket exact CSR: local histogram + scan -> rowstart/deg; scatter into
// the bucket's own dense region (single block => single XCD => no write amp).
// ---------------------------------------------------------------------------
__global__ __launch_bounds__(256) void csr_kernel(const u32* __restrict__ binned,
                                                  const int* __restrict__ bstart,
                                                  int* __restrict__ rowstart,
                                                  int* __restrict__ deg,
                                                  int* __restrict__ edst) {
  __shared__ int cnt[256];
  __shared__ int off[256];
  const int b = blockIdx.x;
  const int beg = bstart[b], end = bstart[b + 1];
  const int t = threadIdx.x;
  cnt[t] = 0;
  __syncthreads();
  for (int i = beg + t; i < end; i += 256)
    atomicAdd(&cnt[binned[i] >> 16], 1);
  __syncthreads();
  const int v = cnt[t];
  int x = v;
  off[t] = v;
  __syncthreads();
  for (int o = 1; o < 256; o <<= 1) {
    const int y = (t >= o) ? off[t - o] : 0;
    __syncthreads();
    x += y;
    off[t] = x;
    __syncthreads();
  }
  off[t] = beg + x - v;  // exclusive, rebased: per-node cursor
  const int node = (b << BSH) + t;
  if (node < NN) { rowstart[node] = beg + x - v; deg[node] = v; }
  __syncthreads();
  for (int i = beg + t; i < end; i += 256) {
    const u32 p = binned[i];
    const int slot = atomicAdd(&off[p >> 16], 1);
    edst[slot] = (int)(p & 0xFFFFu);
  }
}

// ---------------------------------------------------------------------------
// Aggregation: one wave per node (unchanged).
// ---------------------------------------------------------------------------
__global__ __launch_bounds__(256) void agg_kernel(
    const float* __restrict__ h, const float* __restrict__ s1,
    const float* __restrict__ s2, const int* __restrict__ pre,
    const int* __restrict__ deg, const int* __restrict__ edst,
    float* __restrict__ out)
{
  const int lane = threadIdx.x & 63;
  const int node =
      __builtin_amdgcn_readfirstlane(blockIdx.x * 4 + (threadIdx.x >> 6));
  const int base = pre[node];
  const int cnt = deg[node];
  const float s1i = s1[node];

  float acc = 0.f;
  float wsum = 0.f;
  for (int c = 0; c < cnt; c += 64) {
    const int m = min(64, cnt - c);
    int d = 0;
    float w = 0.f;
    if (lane < m) {
      d = edst[base + c + lane];
      const float logit = s1i + s2[d];
      const float lr = logit > 0.f ? logit : ALPHA * logit;
      w = __expf(-lr);
    }
#pragma unroll 4
    for (int l = 0; l < m; ++l) {
      const int dv = __builtin_amdgcn_readlane(d, l);
      const float wv =
          __uint_as_float(__builtin_amdgcn_readlane(__float_as_uint(w), l));
      acc = fmaf(wv, h[(size_t)dv * OUTD + lane], acc);
      wsum += wv;
    }
  }
  const float val = (cnt > 0) ? (acc / wsum) : 0.f;
  const float r = val > 0.f ? val : (__expf(val) - 1.f);  // elu
  out[(size_t)node * OUTD + lane] = r;
}

// ---------------------------------------------------------------------------
extern "C" void kernel_launch(void* const* d_in, const int* in_sizes, int n_in,
                              void* d_out, int out_size, void* d_ws, size_t ws_size,
                              hipStream_t stream) {
  const float* x = (const float*)d_in[0];
  const int* ei = (const int*)d_in[1];
  const float* W = (const float*)d_in[2];
  const float* a = (const float*)d_in[3];
  float* out = (float*)d_out;

  // workspace layout (~26.6 MB)
  float* h = (float*)d_ws;              // NN*64 fp32
  float* s1 = h + (size_t)NN * OUTD;    // NN
  float* s2 = s1 + NN;                  // NN
  int* rowstart = (int*)(s2 + NN);      // NN
  int* deg = rowstart + NN;             // NN
  int* bhist = deg + NN;                // NB
  int* bstart = bhist + NB;             // NB+1
  int* gcursor = bstart + NB + 1;       // NB
  u32* binned = (u32*)(gcursor + NB);   // NE
  int* edst = (int*)(binned + NE);      // NE

  const int* src = ei;
  const int* dst = ei + NE;

  hipMemsetAsync(bhist, 0, NB * sizeof(int), stream);
  hipLaunchKernelGGL(gemm_h_kernel, dim3(NN / 16), dim3(256), 0, stream,
                     x, W, a, h, s1, s2);
  hipLaunchKernelGGL(hist_kernel, dim3(P1_BLOCKS), dim3(256), 0, stream,
                     src, bhist);
  hipLaunchKernelGGL(bscan_kernel, dim3(1), dim3(256), 0, stream,
                     bhist, bstart, gcursor);
  hipLaunchKernelGGL(bin_kernel, dim3(P1_BLOCKS), dim3(256), 0, stream,
                     src, dst, gcursor, binned);
  hipLaunchKernelGGL(csr_kernel, dim3(NB), dim3(256), 0, stream,
                     binned, bstart, rowstart, deg, edst);
  hipLaunchKernelGGL(agg_kernel, dim3(NN / 4), dim3(256), 0, stream,
                     h, s1, s2, rowstart, deg, edst, out);
}

// Round 4
// 326.851 us; speedup vs baseline: 2.5097x; 2.5097x over previous
//
#include <hip/hip_runtime.h>

#define NN 50000
#define NE 1600000
#define DIM 256
#define OUTD 64
#define ALPHA 0.2f

#define BSH 8                 // bucket = src >> 8 (256 nodes/bucket)
#define NB ((NN + 255) >> 8)  // 196 coarse buckets
#define P1 1000               // binning blocks
#define EPB (NE / P1)         // 1600 edges per block (exact)
#define TOT (NB * P1)         // 196000 (p,b) pairs
#define S1B ((TOT + 255) / 256)  // 766 scan blocks

typedef unsigned int u32;

// ---------------------------------------------------------------------------
// h = x @ W  (fp32), plus per-node logit partials s1 = h.a[:64], s2 = h.a[64:]
// ---------------------------------------------------------------------------
__global__ __launch_bounds__(256) void gemm_h_kernel(
    const float* __restrict__ x, const float* __restrict__ W,
    const float* __restrict__ a, float* __restrict__ h,
    float* __restrict__ s1, float* __restrict__ s2)
{
  __shared__ float Wl[DIM][OUTD];  // 64 KB
  const int t = threadIdx.x;
  for (int i = t; i < DIM * OUTD; i += 256) Wl[i >> 6][i & 63] = W[i];
  __syncthreads();

  const int o = t & 63;
  const int rsub = __builtin_amdgcn_readfirstlane(t >> 6);  // wave id, SGPR
  const int row0 = blockIdx.x * 16;

  const float4* xr0 = (const float4*)(x + (size_t)(row0 + rsub) * DIM);
  const float4* xr1 = xr0 + DIM;
  const float4* xr2 = xr0 + 2 * DIM;
  const float4* xr3 = xr0 + 3 * DIM;

  float acc0 = 0.f, acc1 = 0.f, acc2 = 0.f, acc3 = 0.f;
#pragma unroll 2
  for (int k4 = 0; k4 < DIM / 4; ++k4) {
    const float4 u0 = xr0[k4], u1 = xr1[k4], u2 = xr2[k4], u3 = xr3[k4];
    const float w0 = Wl[4 * k4 + 0][o];
    const float w1 = Wl[4 * k4 + 1][o];
    const float w2 = Wl[4 * k4 + 2][o];
    const float w3 = Wl[4 * k4 + 3][o];
    acc0 = fmaf(u0.x, w0, acc0); acc0 = fmaf(u0.y, w1, acc0);
    acc0 = fmaf(u0.z, w2, acc0); acc0 = fmaf(u0.w, w3, acc0);
    acc1 = fmaf(u1.x, w0, acc1); acc1 = fmaf(u1.y, w1, acc1);
    acc1 = fmaf(u1.z, w2, acc1); acc1 = fmaf(u1.w, w3, acc1);
    acc2 = fmaf(u2.x, w0, acc2); acc2 = fmaf(u2.y, w1, acc2);
    acc2 = fmaf(u2.z, w2, acc2); acc2 = fmaf(u2.w, w3, acc2);
    acc3 = fmaf(u3.x, w0, acc3); acc3 = fmaf(u3.y, w1, acc3);
    acc3 = fmaf(u3.z, w2, acc3); acc3 = fmaf(u3.w, w3, acc3);
  }

  const float a1 = a[o];
  const float a2 = a[OUTD + o];
  float accs[4] = {acc0, acc1, acc2, acc3};
#pragma unroll
  for (int j = 0; j < 4; ++j) {
    const int r = row0 + rsub + 4 * j;
    h[(size_t)r * OUTD + o] = accs[j];
    float p1 = accs[j] * a1;
    float p2 = accs[j] * a2;
    for (int off = 32; off > 0; off >>= 1) {
      p1 += __shfl_xor(p1, off);
      p2 += __shfl_xor(p2, off);
    }
    if (o == 0) { s1[r] = p1; s2[r] = p2; }
  }
}

// ---------------------------------------------------------------------------
// Per-block coarse histogram -> bcnt[p][b] (coalesced store, no global atomics)
// ---------------------------------------------------------------------------
__global__ __launch_bounds__(256) void hist_kernel(const int* __restrict__ src,
                                                   int* __restrict__ bcnt) {
  __shared__ int lh[NB];
  const int t = threadIdx.x;
  for (int i = t; i < NB; i += 256) lh[i] = 0;
  __syncthreads();
  const int base = blockIdx.x * EPB;
  for (int i = t; i < EPB; i += 256)
    atomicAdd(&lh[src[base + i] >> BSH], 1);
  __syncthreads();
  for (int i = t; i < NB; i += 256)
    bcnt[(size_t)blockIdx.x * NB + i] = lh[i];
}

// ---------------------------------------------------------------------------
// Scan of bcnt in b-major order (e = b*P1 + p), 3-kernel exclusive scan.
// Result binoff[e] = start of the private range for (block p, bucket b).
// ---------------------------------------------------------------------------
__global__ __launch_bounds__(256) void scan1_kernel(const int* __restrict__ bcnt,
                                                    int* __restrict__ binoff,
                                                    int* __restrict__ bsums) {
  __shared__ int tmp[256];
  const int t = threadIdx.x;
  const int e = blockIdx.x * 256 + t;
  int v = 0;
  if (e < TOT) {
    const int b = e / P1;
    const int p = e - b * P1;
    v = bcnt[(size_t)p * NB + b];  // strided gather, L2-resident
  }
  int x = v;
  tmp[t] = v;
  __syncthreads();
  for (int off = 1; off < 256; off <<= 1) {
    const int y = (t >= off) ? tmp[t - off] : 0;
    __syncthreads();
    x += y;
    tmp[t] = x;
    __syncthreads();
  }
  if (e < TOT) binoff[e] = x - v;       // exclusive within block
  if (t == 255) bsums[blockIdx.x] = x;  // block total
}

__global__ __launch_bounds__(1024) void scan2_kernel(int* __restrict__ bsums) {
  __shared__ int tmp[1024];
  const int t = threadIdx.x;
  const int v = (t < S1B) ? bsums[t] : 0;
  int x = v;
  tmp[t] = v;
  __syncthreads();
  for (int off = 1; off < 1024; off <<= 1) {
    const int y = (t >= off) ? tmp[t - off] : 0;
    __syncthreads();
    x += y;
    tmp[t] = x;
    __syncthreads();
  }
  if (t < S1B) bsums[t] = x - v;  // exclusive block offsets
}

__global__ __launch_bounds__(256) void scan3_kernel(int* __restrict__ binoff,
                                                    const int* __restrict__ bsums,
                                                    int* __restrict__ bstart) {
  const int e = blockIdx.x * 256 + threadIdx.x;
  if (e < TOT) {
    const int val = binoff[e] + bsums[blockIdx.x];
    binoff[e] = val;
    const int b = e / P1;
    if (e == b * P1) bstart[b] = val;  // p == 0
  }
  if (e == 0) bstart[NB] = NE;
}

// ---------------------------------------------------------------------------
// Binning: each block appends each edge into its OWN private range of
// `binned` for that edge's bucket. One ds_add_rtn + one direct global 4B
// write per edge; no staging buffer, no flush, no global atomics. A block's
// writes land densely in lines owned by its XCD -> write amp ~1.
// packed = (src&255)<<16 | dst  (dst < 65536).
// ---------------------------------------------------------------------------
__global__ __launch_bounds__(256) void bin_kernel(const int* __restrict__ src,
                                                  const int* __restrict__ dst,
                                                  const int* __restrict__ binoff,
                                                  u32* __restrict__ binned) {
  __shared__ int lcur[NB];
  const int t = threadIdx.x;
  for (int b = t; b < NB; b += 256)
    lcur[b] = binoff[(size_t)b * P1 + blockIdx.x];
  __syncthreads();
  const int base = blockIdx.x * EPB;
  for (int i = t; i < EPB; i += 256) {
    const int s = src[base + i];
    const u32 packed = ((u32)(s & 255) << 16) | (u32)dst[base + i];
    const int pos = atomicAdd(&lcur[s >> BSH], 1);
    binned[pos] = packed;
  }
}

// ---------------------------------------------------------------------------
// Per-bucket exact CSR: local histogram + scan -> rowstart/deg; scatter into
// the bucket's own dense region (single block => single XCD => no write amp).
// ---------------------------------------------------------------------------
__global__ __launch_bounds__(256) void csr_kernel(const u32* __restrict__ binned,
                                                  const int* __restrict__ bstart,
                                                  int* __restrict__ rowstart,
                                                  int* __restrict__ deg,
                                                  int* __restrict__ edst) {
  __shared__ int cnt[256];
  __shared__ int off[256];
  const int b = blockIdx.x;
  const int beg = bstart[b], end = bstart[b + 1];
  const int t = threadIdx.x;
  cnt[t] = 0;
  __syncthreads();
  for (int i = beg + t; i < end; i += 256)
    atomicAdd(&cnt[binned[i] >> 16], 1);
  __syncthreads();
  const int v = cnt[t];
  int x = v;
  off[t] = v;
  __syncthreads();
  for (int o = 1; o < 256; o <<= 1) {
    const int y = (t >= o) ? off[t - o] : 0;
    __syncthreads();
    x += y;
    off[t] = x;
    __syncthreads();
  }
  off[t] = beg + x - v;  // exclusive, rebased: per-node cursor
  const int node = (b << BSH) + t;
  if (node < NN) { rowstart[node] = beg + x - v; deg[node] = v; }
  __syncthreads();
  for (int i = beg + t; i < end; i += 256) {
    const u32 p = binned[i];
    const int slot = atomicAdd(&off[p >> 16], 1);
    edst[slot] = (int)(p & 0xFFFFu);
  }
}

// ---------------------------------------------------------------------------
// Aggregation: one wave per node.
// ---------------------------------------------------------------------------
__global__ __launch_bounds__(256) void agg_kernel(
    const float* __restrict__ h, const float* __restrict__ s1,
    const float* __restrict__ s2, const int* __restrict__ pre,
    const int* __restrict__ deg, const int* __restrict__ edst,
    float* __restrict__ out)
{
  const int lane = threadIdx.x & 63;
  const int node =
      __builtin_amdgcn_readfirstlane(blockIdx.x * 4 + (threadIdx.x >> 6));
  const int base = pre[node];
  const int cnt = deg[node];
  const float s1i = s1[node];

  float acc = 0.f;
  float wsum = 0.f;
  for (int c = 0; c < cnt; c += 64) {
    const int m = min(64, cnt - c);
    int d = 0;
    float w = 0.f;
    if (lane < m) {
      d = edst[base + c + lane];
      const float logit = s1i + s2[d];
      const float lr = logit > 0.f ? logit : ALPHA * logit;
      w = __expf(-lr);
    }
#pragma unroll 4
    for (int l = 0; l < m; ++l) {
      const int dv = __builtin_amdgcn_readlane(d, l);
      const float wv =
          __uint_as_float(__builtin_amdgcn_readlane(__float_as_uint(w), l));
      acc = fmaf(wv, h[(size_t)dv * OUTD + lane], acc);
      wsum += wv;
    }
  }
  const float val = (cnt > 0) ? (acc / wsum) : 0.f;
  const float r = val > 0.f ? val : (__expf(val) - 1.f);  // elu
  out[(size_t)node * OUTD + lane] = r;
}

// ---------------------------------------------------------------------------
extern "C" void kernel_launch(void* const* d_in, const int* in_sizes, int n_in,
                              void* d_out, int out_size, void* d_ws, size_t ws_size,
                              hipStream_t stream) {
  const float* x = (const float*)d_in[0];
  const int* ei = (const int*)d_in[1];
  const float* W = (const float*)d_in[2];
  const float* a = (const float*)d_in[3];
  float* out = (float*)d_out;

  // workspace layout (~28 MB)
  float* h = (float*)d_ws;              // NN*64
  float* s1 = h + (size_t)NN * OUTD;    // NN
  float* s2 = s1 + NN;                  // NN
  int* rowstart = (int*)(s2 + NN);      // NN
  int* deg = rowstart + NN;             // NN
  int* bcnt = deg + NN;                 // P1*NB
  int* binoff = bcnt + TOT;             // P1*NB
  int* bsums = binoff + TOT;            // S1B
  int* bstart = bsums + S1B;            // NB+1
  u32* binned = (u32*)(bstart + NB + 1);  // NE
  int* edst = (int*)(binned + NE);      // NE

  const int* src = ei;
  const int* dst = ei + NE;

  hipLaunchKernelGGL(gemm_h_kernel, dim3(NN / 16), dim3(256), 0, stream,
                     x, W, a, h, s1, s2);
  hipLaunchKernelGGL(hist_kernel, dim3(P1), dim3(256), 0, stream, src, bcnt);
  hipLaunchKernelGGL(scan1_kernel, dim3(S1B), dim3(256), 0, stream,
                     bcnt, binoff, bsums);
  hipLaunchKernelGGL(scan2_kernel, dim3(1), dim3(1024), 0, stream, bsums);
  hipLaunchKernelGGL(scan3_kernel, dim3(S1B), dim3(256), 0, stream,
                     binoff, bsums, bstart);
  hipLaunchKernelGGL(bin_kernel, dim3(P1), dim3(256), 0, stream,
                     src, dst, binoff, binned);
  hipLaunchKernelGGL(csr_kernel, dim3(NB), dim3(256), 0, stream,
                     binned, bstart, rowstart, deg, edst);
  hipLaunchKernelGGL(agg_kernel, dim3(NN / 4), dim3(256), 0, stream,
                     h, s1, s2, rowstart, deg, edst, out);
}